// Round 1
// baseline (225.854 us; speedup 1.0000x reference)
//
#include <hip/hip_runtime.h>

#define HW 1659      // 21*79
#define PADID 4096
#define EMB 20
#define HID 32
#define MAXLEN 64

// ---------------- Kernel 1: presence bitmap -> bag -> emb gather ----------------
__global__ __launch_bounds__(256) void bag_emb_kernel(
    const int* __restrict__ chars, const int* __restrict__ colors,
    const float* __restrict__ emb_table,
    float* __restrict__ out_emb, float* __restrict__ out_bag)
{
    __shared__ unsigned bm[128];
    __shared__ int sc[128];
    __shared__ int bagl[64];

    const int b = blockIdx.x;
    const int tid = threadIdx.x;

    if (tid < 128) bm[tid] = 0u;
    if (tid < 64) bagl[tid] = PADID;
    __syncthreads();

    // presence bitmap over 4096 glyph ids
    const int base = b * HW;
    for (int i = tid; i < HW; i += 256) {
        int g = (chars[base + i] << 4) + colors[base + i];   // 0..4095
        atomicOr(&bm[g >> 5], 1u << (g & 31));
    }
    __syncthreads();

    // popcount + inclusive prefix scan over 128 words (Hillis-Steele)
    int cnt = 0;
    if (tid < 128) { cnt = __popc(bm[tid]); sc[tid] = cnt; }
    __syncthreads();
    for (int d = 1; d < 128; d <<= 1) {
        int v = 0;
        if (tid >= d && tid < 128) v = sc[tid - d];
        __syncthreads();
        if (tid < 128) sc[tid] += v;
        __syncthreads();
    }

    // extract the (up to) 64 smallest present ids
    if (tid < 128) {
        unsigned w = bm[tid];
        int p = sc[tid] - cnt;   // exclusive prefix
        while (w && p < 64) {
            int bit = __ffs(w) - 1;
            bagl[p++] = (tid << 5) | bit;
            w &= w - 1;
        }
    }
    __syncthreads();

    // write bag (as float, harness reads output buffer as fp32)
    if (tid < 64) out_bag[(size_t)b * 64 + tid] = (float)bagl[tid];

    // gather embeddings: 64 rows x 20 floats (emb_table row 4096 is zeros)
    for (int idx = tid; idx < MAXLEN * EMB; idx += 256) {
        int t = idx / EMB;
        int c = idx - t * EMB;
        int row = bagl[t];
        out_emb[(size_t)b * (MAXLEN * EMB) + idx] = emb_table[row * EMB + c];
    }
}

// ---------------- Kernel 2: packed RNN, thread = (sample-in-block, hidden) -----
__global__ __launch_bounds__(256) void rnn_kernel(
    const float* __restrict__ emb, const float* __restrict__ bagf,
    const float* __restrict__ W_ih, const float* __restrict__ W_hh,
    const float* __restrict__ b_ih, const float* __restrict__ b_hh,
    float* __restrict__ out_h)
{
    // 8 samples per block; 32 threads (one per hidden unit) per sample.
    // h rows padded to 36 floats -> float4 broadcast reads are bank-conflict-free.
    __shared__ float hbuf[8][36];

    const int tid = threadIdx.x;
    const int ib = tid >> 5;
    const int j  = tid & 31;
    const int b  = blockIdx.x * 8 + ib;

    float wih[EMB];
#pragma unroll
    for (int k = 0; k < EMB; k++) wih[k] = W_ih[j * EMB + k];
    float whh[HID];
#pragma unroll
    for (int k = 0; k < HID; k++) whh[k] = W_hh[j * HID + k];
    const float sbias = b_ih[j] + b_hh[j];

    hbuf[ib][j] = 0.f;
    float h = 0.f;

    const float* xb = emb + (size_t)b * (MAXLEN * EMB);
    const float* bp = bagf + (size_t)b * 64;

    // prefetch x_0 (20 floats = 5 float4; base is 16B-aligned: b*1280*4)
    float4 xc[5];
#pragma unroll
    for (int m = 0; m < 5; m++) xc[m] = ((const float4*)xb)[m];

    __syncthreads();

    for (int t = 0; t < MAXLEN; t++) {
        float bagv = bp[t];   // broadcast; padding (4096) <=> t >= length

        // prefetch x_{t+1} (clamped; stays in-bounds of d_out)
        const int tn = (t + 1 < MAXLEN) ? (t + 1) : t;
        float4 xn[5];
#pragma unroll
        for (int m = 0; m < 5; m++) xn[m] = ((const float4*)(xb + tn * EMB))[m];

        float s = sbias;
#pragma unroll
        for (int m = 0; m < 5; m++) {
            s += wih[4*m+0]*xc[m].x + wih[4*m+1]*xc[m].y
               + wih[4*m+2]*xc[m].z + wih[4*m+3]*xc[m].w;
        }
        const float4* hb4 = (const float4*)hbuf[ib];
#pragma unroll
        for (int m = 0; m < 8; m++) {
            float4 hv = hb4[m];
            s += whh[4*m+0]*hv.x + whh[4*m+1]*hv.y
               + whh[4*m+2]*hv.z + whh[4*m+3]*hv.w;
        }
        s = tanhf(s);

        __syncthreads();                 // all h reads done
        if (bagv < 4095.5f) {            // t < length
            h = s;
            hbuf[ib][j] = s;
        }
        __syncthreads();                 // h writes visible

#pragma unroll
        for (int m = 0; m < 5; m++) xc[m] = xn[m];
    }

    out_h[(size_t)b * HID + j] = h;
}

extern "C" void kernel_launch(void* const* d_in, const int* in_sizes, int n_in,
                              void* d_out, int out_size, void* d_ws, size_t ws_size,
                              hipStream_t stream) {
    const int*   chars     = (const int*)d_in[0];
    const int*   colors    = (const int*)d_in[1];
    const float* emb_table = (const float*)d_in[2];
    const float* W_ih      = (const float*)d_in[3];
    const float* W_hh      = (const float*)d_in[4];
    const float* b_ih      = (const float*)d_in[5];
    const float* b_hh      = (const float*)d_in[6];

    const int B = in_sizes[0] / HW;      // 8192

    float* out     = (float*)d_out;
    float* out_h   = out;                                    // [B, 32]
    float* out_emb = out + (size_t)B * HID;                  // [B, 64, 20]
    float* out_bag = out_emb + (size_t)B * MAXLEN * EMB;     // [B, 64]

    bag_emb_kernel<<<B, 256, 0, stream>>>(chars, colors, emb_table, out_emb, out_bag);
    rnn_kernel<<<B / 8, 256, 0, stream>>>(out_emb, out_bag, W_ih, W_hh, b_ih, b_hh, out_h);
}

// Round 3
// 211.469 us; speedup vs baseline: 1.0680x; 1.0680x over previous
//
#include <hip/hip_runtime.h>

#define HW 1659      // 21*79
#define PADID 4096
#define EMB 20
#define HID 32
#define MAXLEN 64

// ---------------- Kernel 1: presence bitmap -> bag -> emb gather ----------------
// Proven-correct R1 structure: block per sample, standard __syncthreads.
__global__ __launch_bounds__(256) void bag_emb_kernel(
    const int* __restrict__ chars, const int* __restrict__ colors,
    const float* __restrict__ emb_table,
    float* __restrict__ out_emb, float* __restrict__ out_bag)
{
    __shared__ unsigned bm[128];
    __shared__ int sc[128];
    __shared__ int bagl[64];

    const int b = blockIdx.x;
    const int tid = threadIdx.x;

    if (tid < 128) bm[tid] = 0u;
    if (tid < 64) bagl[tid] = PADID;
    __syncthreads();

    // presence bitmap over 4096 glyph ids
    const int base = b * HW;
    for (int i = tid; i < HW; i += 256) {
        int g = (chars[base + i] << 4) + colors[base + i];   // 0..4095
        atomicOr(&bm[g >> 5], 1u << (g & 31));
    }
    __syncthreads();

    // popcount + inclusive prefix scan over 128 words (Hillis-Steele)
    int cnt = 0;
    if (tid < 128) { cnt = __popc(bm[tid]); sc[tid] = cnt; }
    __syncthreads();
    for (int d = 1; d < 128; d <<= 1) {
        int v = 0;
        if (tid >= d && tid < 128) v = sc[tid - d];
        __syncthreads();
        if (tid < 128) sc[tid] += v;
        __syncthreads();
    }

    // extract the (up to) 64 smallest present ids
    if (tid < 128) {
        unsigned w = bm[tid];
        int p = sc[tid] - cnt;   // exclusive prefix
        while (w && p < 64) {
            int bit = __ffs(w) - 1;
            bagl[p++] = (tid << 5) | bit;
            w &= w - 1;
        }
    }
    __syncthreads();

    if (tid < 64) out_bag[(size_t)b * 64 + tid] = (float)bagl[tid];

    // vectorized gather: emb rows are 80 B = 5 float4, table base 16B-aligned;
    // out_emb sample row = 64*20 floats = 320 float4, offset b*1280 floats aligned.
    const float4* tab4 = (const float4*)emb_table;
    float4* dst4 = (float4*)(out_emb + (size_t)b * (MAXLEN * EMB));
    for (int q = tid; q < MAXLEN * 5; q += 256) {
        int t = q / 5;                 // compiler magic-div
        int m = q - t * 5;
        int row = bagl[t];             // row 4096 is the zero padding row
        dst4[q] = tab4[row * 5 + m];
    }
}

// ---------------- Kernel 2: packed RNN ----------------
// 8 samples/block, thread=(sample,hidden). __launch_bounds__(256,4): <=128 VGPR
// so the 52 weight floats stay register-resident (R1's 64-VGPR cap forced
// per-step reloads). Double-buffered h -> ONE __syncthreads per step.
__global__ __launch_bounds__(256, 4) void rnn_kernel(
    const float* __restrict__ emb, const float* __restrict__ bagf,
    const float* __restrict__ W_ih, const float* __restrict__ W_hh,
    const float* __restrict__ b_ih, const float* __restrict__ b_hh,
    float* __restrict__ out_h)
{
    __shared__ float hbuf[2][8][36];   // 36-float rows: float4 reads conflict-free

    const int tid = threadIdx.x;
    const int ib  = tid >> 5;          // sample slot in block
    const int j   = tid & 31;          // hidden unit
    const int b   = blockIdx.x * 8 + ib;

    float wih[EMB];
#pragma unroll
    for (int k = 0; k < EMB; k++) wih[k] = W_ih[j * EMB + k];
    float whh[HID];
#pragma unroll
    for (int k = 0; k < HID; k++) whh[k] = W_hh[j * HID + k];
    const float sbias = b_ih[j] + b_hh[j];

    // sequence length from sorted bag via one ballot (padding id == 4096)
    const float* bp = bagf + (size_t)b * 64;
    unsigned long long m0 = __ballot(bp[j]      < 4095.5f);
    unsigned long long m1 = __ballot(bp[32 + j] < 4095.5f);
    const int half = ib & 1;           // which 32-lane half holds my sample
    const int len = __popc((unsigned)(m0 >> (half * 32)))
                  + __popc((unsigned)(m1 >> (half * 32)));

    hbuf[0][ib][j] = 0.f;
    float h = 0.f;
    const float* xb = emb + (size_t)b * (MAXLEN * EMB);

    __syncthreads();

    int cur = 0;
    for (int t = 0; t < MAXLEN; t++) {
        // issue x_t loads first (L2-hot); latency covered by the h-dot below
        float4 x0 = ((const float4*)(xb + t * EMB))[0];
        float4 x1 = ((const float4*)(xb + t * EMB))[1];
        float4 x2 = ((const float4*)(xb + t * EMB))[2];
        float4 x3 = ((const float4*)(xb + t * EMB))[3];
        float4 x4 = ((const float4*)(xb + t * EMB))[4];

        float s = sbias;
        const float4* hb4 = (const float4*)hbuf[cur][ib];
#pragma unroll
        for (int m = 0; m < 8; m++) {
            float4 hv = hb4[m];
            s += whh[4*m+0]*hv.x + whh[4*m+1]*hv.y
               + whh[4*m+2]*hv.z + whh[4*m+3]*hv.w;
        }
        s += wih[0]*x0.x + wih[1]*x0.y + wih[2]*x0.z + wih[3]*x0.w;
        s += wih[4]*x1.x + wih[5]*x1.y + wih[6]*x1.z + wih[7]*x1.w;
        s += wih[8]*x2.x + wih[9]*x2.y + wih[10]*x2.z + wih[11]*x2.w;
        s += wih[12]*x3.x + wih[13]*x3.y + wih[14]*x3.z + wih[15]*x3.w;
        s += wih[16]*x4.x + wih[17]*x4.y + wih[18]*x4.z + wih[19]*x4.w;

        // fast tanh: (e^{2s}-1)/(e^{2s}+1), clamped so exp never overflows
        s = fminf(fmaxf(s, -9.f), 9.f);
        float e = __expf(2.f * s);
        float th = (e - 1.f) * __builtin_amdgcn_rcpf(e + 1.f);

        h = (t < len) ? th : h;            // freeze past sequence length

        hbuf[cur ^ 1][ib][j] = h;          // write NEXT buffer (read buf untouched)
        __syncthreads();                   // one barrier per step
        cur ^= 1;
    }

    out_h[(size_t)b * HID + j] = h;
}

extern "C" void kernel_launch(void* const* d_in, const int* in_sizes, int n_in,
                              void* d_out, int out_size, void* d_ws, size_t ws_size,
                              hipStream_t stream) {
    const int*   chars     = (const int*)d_in[0];
    const int*   colors    = (const int*)d_in[1];
    const float* emb_table = (const float*)d_in[2];
    const float* W_ih      = (const float*)d_in[3];
    const float* W_hh      = (const float*)d_in[4];
    const float* b_ih      = (const float*)d_in[5];
    const float* b_hh      = (const float*)d_in[6];

    const int B = in_sizes[0] / HW;      // 8192

    float* out     = (float*)d_out;
    float* out_h   = out;                                    // [B, 32]
    float* out_emb = out + (size_t)B * HID;                  // [B, 64, 20]
    float* out_bag = out_emb + (size_t)B * MAXLEN * EMB;     // [B, 64]

    bag_emb_kernel<<<B, 256, 0, stream>>>(chars, colors, emb_table, out_emb, out_bag);
    rnn_kernel<<<B / 8, 256, 0, stream>>>(out_emb, out_bag, W_ih, W_hh, b_ih, b_hh, out_h);
}

// Round 4
// 198.799 us; speedup vs baseline: 1.1361x; 1.0637x over previous
//
#include <hip/hip_runtime.h>

#define HW 1659      // 21*79
#define PADID 4096
#define EMB 20
#define HID 32
#define MAXLEN 64

// ---------------- Kernel 1: presence bytes -> scan -> bag -> emb gather --------
// Byte-store presence (idempotent, no atomics), int4 glyph loads, shuffle scan.
__global__ __launch_bounds__(256) void bag_emb_kernel(
    const int* __restrict__ chars, const int* __restrict__ colors,
    const float* __restrict__ emb_table,
    float* __restrict__ out_emb, float* __restrict__ out_bag)
{
    __shared__ unsigned char pres[4096];
    __shared__ int bagl[64];
    __shared__ int wsum[4];

    const int b   = blockIdx.x;
    const int tid = threadIdx.x;
    const int lane = tid & 63;
    const int wv   = tid >> 6;

    // zero presence bytes (256 * 16B = 4096B exactly)
    ((uint4*)pres)[tid] = make_uint4(0u, 0u, 0u, 0u);
    if (tid < 64) bagl[tid] = PADID;
    __syncthreads();

    // ---- presence: pres[g] = 1 (benign races, no RMW) ----
    const int base = b * HW;
    const int pe = (4 - (base & 3)) & 3;          // peel to 16B alignment
    if (tid < pe) {
        int g = (chars[base + tid] << 4) + colors[base + tid];
        pres[g] = 1;
    }
    const int nv = (HW - pe) >> 2;                // int4 groups (==414)
    const int nt = HW - pe - (nv << 2);           // tail 0..3
    const int4* c4 = (const int4*)(chars + base + pe);
    const int4* k4 = (const int4*)(colors + base + pe);
    for (int v = tid; v < nv; v += 256) {
        int4 c = c4[v], k = k4[v];
        pres[(c.x << 4) + k.x] = 1;
        pres[(c.y << 4) + k.y] = 1;
        pres[(c.z << 4) + k.z] = 1;
        pres[(c.w << 4) + k.w] = 1;
    }
    if (tid < nt) {
        int i = base + pe + (nv << 2) + tid;
        int g = (chars[i] << 4) + colors[i];
        pres[g] = 1;
    }
    __syncthreads();

    // ---- each thread owns 16 ids; count + block exclusive scan ----
    uint4 w4 = ((const uint4*)pres)[tid];
    const unsigned M = 0x01010101u;
    int cnt = __popc(w4.x & M) + __popc(w4.y & M)
            + __popc(w4.z & M) + __popc(w4.w & M);

    int pre = cnt;                                 // wave inclusive scan
#pragma unroll
    for (int d = 1; d < 64; d <<= 1) {
        int v = __shfl_up(pre, d, 64);
        if (lane >= d) pre += v;
    }
    if (lane == 63) wsum[wv] = pre;
    __syncthreads();
    int wbase = 0;
#pragma unroll
    for (int w2 = 0; w2 < 4; w2++) wbase += (w2 < wv) ? wsum[w2] : 0;
    int p = wbase + pre - cnt;                     // exclusive prefix

    // ---- extract ids into bagl (first 64 smallest overall) ----
    unsigned wrd[4] = {w4.x, w4.y, w4.z, w4.w};
#pragma unroll
    for (int c = 0; c < 4; c++) {
#pragma unroll
        for (int k = 0; k < 4; k++) {
            if ((wrd[c] >> (8 * k)) & 1) {
                if (p < 64) bagl[p] = 16 * tid + 4 * c + k;
                p++;
            }
        }
    }
    __syncthreads();

    if (tid < 64) out_bag[(size_t)b * 64 + tid] = (float)bagl[tid];

    // ---- gather: emb rows = 5 float4 (row 4096 is the zero row) ----
    const float4* tab4 = (const float4*)emb_table;
    float4* dst4 = (float4*)(out_emb + (size_t)b * (MAXLEN * EMB));
    for (int q = tid; q < MAXLEN * 5; q += 256) {
        int t = q / 5;
        int m = q - t * 5;
        int row = bagl[t];
        dst4[q] = tab4[row * 5 + m];
    }
}

// ---------------- Kernel 2: packed RNN, wave-private, ZERO block barriers ------
// 4 samples/block (128 thr) = 2 per wave; h rows are wave-private so a
// wave-level LDS fence (s_waitcnt lgkmcnt(0) + memory clobber) replaces
// __syncthreads. Weights pinned in VGPRs via asm (stops remat reloads).
__global__ __launch_bounds__(128, 4) void rnn_kernel(
    const float* __restrict__ emb, const float* __restrict__ bagf,
    const float* __restrict__ W_ih, const float* __restrict__ W_hh,
    const float* __restrict__ b_ih, const float* __restrict__ b_hh,
    float* __restrict__ out_h)
{
    __shared__ float hbuf[4][32];   // row per sample; 2 rows per wave (disjoint)

    const int tid = threadIdx.x;
    const int ib  = tid >> 5;          // sample slot 0..3
    const int j   = tid & 31;          // hidden unit
    const int b   = blockIdx.x * 4 + ib;

    float wih[EMB];
#pragma unroll
    for (int k = 0; k < EMB; k++) wih[k] = W_ih[j * EMB + k];
    float whh[HID];
#pragma unroll
    for (int k = 0; k < HID; k++) whh[k] = W_hh[j * HID + k];
    // pin: make defs opaque so the allocator can't rematerialize the loads
#pragma unroll
    for (int k = 0; k < EMB; k++) asm("" : "+v"(wih[k]));
#pragma unroll
    for (int k = 0; k < HID; k++) asm("" : "+v"(whh[k]));
    const float sbias = b_ih[j] + b_hh[j];

    // sequence length from sorted bag via one ballot (padding id == 4096)
    const float* bp = bagf + (size_t)b * 64;
    unsigned long long m0 = __ballot(bp[j]      < 4095.5f);
    unsigned long long m1 = __ballot(bp[32 + j] < 4095.5f);
    const int half = ib & 1;           // which 32-lane half holds my sample
    const int len = __popc((unsigned)(m0 >> (half * 32)))
                  + __popc((unsigned)(m1 >> (half * 32)));

    hbuf[ib][j] = 0.f;
    asm volatile("s_waitcnt lgkmcnt(0)" ::: "memory");   // wave-local fence

    float h = 0.f;
    const float* xb = emb + (size_t)b * (MAXLEN * EMB);

    for (int t = 0; t < MAXLEN; t++) {
        const float4* xp = (const float4*)(xb + t * EMB);
        float4 x0 = xp[0], x1 = xp[1], x2 = xp[2], x3 = xp[3], x4 = xp[4];

        float s = sbias;
        const float4* hb4 = (const float4*)hbuf[ib];
#pragma unroll
        for (int m = 0; m < 8; m++) {
            float4 hv = hb4[m];
            s += whh[4*m+0]*hv.x + whh[4*m+1]*hv.y
               + whh[4*m+2]*hv.z + whh[4*m+3]*hv.w;
        }
        s += wih[0]*x0.x + wih[1]*x0.y + wih[2]*x0.z + wih[3]*x0.w;
        s += wih[4]*x1.x + wih[5]*x1.y + wih[6]*x1.z + wih[7]*x1.w;
        s += wih[8]*x2.x + wih[9]*x2.y + wih[10]*x2.z + wih[11]*x2.w;
        s += wih[12]*x3.x + wih[13]*x3.y + wih[14]*x3.z + wih[15]*x3.w;
        s += wih[16]*x4.x + wih[17]*x4.y + wih[18]*x4.z + wih[19]*x4.w;

        // fast tanh: (e^{2s}-1)/(e^{2s}+1), clamped so exp never overflows
        s = fminf(fmaxf(s, -9.f), 9.f);
        float e = __expf(2.f * s);
        float th = (e - 1.f) * __builtin_amdgcn_rcpf(e + 1.f);

        h = (t < len) ? th : h;            // freeze past sequence length

        hbuf[ib][j] = h;
        asm volatile("s_waitcnt lgkmcnt(0)" ::: "memory");  // write visible to
                                                            // next-iter reads
    }

    out_h[(size_t)b * HID + j] = h;
}

extern "C" void kernel_launch(void* const* d_in, const int* in_sizes, int n_in,
                              void* d_out, int out_size, void* d_ws, size_t ws_size,
                              hipStream_t stream) {
    const int*   chars     = (const int*)d_in[0];
    const int*   colors    = (const int*)d_in[1];
    const float* emb_table = (const float*)d_in[2];
    const float* W_ih      = (const float*)d_in[3];
    const float* W_hh      = (const float*)d_in[4];
    const float* b_ih      = (const float*)d_in[5];
    const float* b_hh      = (const float*)d_in[6];

    const int B = in_sizes[0] / HW;      // 8192

    float* out     = (float*)d_out;
    float* out_h   = out;                                    // [B, 32]
    float* out_emb = out + (size_t)B * HID;                  // [B, 64, 20]
    float* out_bag = out_emb + (size_t)B * MAXLEN * EMB;     // [B, 64]

    bag_emb_kernel<<<B, 256, 0, stream>>>(chars, colors, emb_table, out_emb, out_bag);
    rnn_kernel<<<B / 4, 128, 0, stream>>>(out_emb, out_bag, W_ih, W_hh, b_ih, b_hh, out_h);
}